// Round 1
// 723.049 us; speedup vs baseline: 1.1590x; 1.1590x over previous
//
#include <hip/hip_runtime.h>
#include <cstdint>
#include <cstddef>

#define B_   4096   // batch
#define ISZ  1024   // input size
#define SW   4096   // state width (input state last dim)
#define OHW  2048   // output hidden width (4 depths x 512)
#define HU_  512    // hidden units per (depth,stack)
#define NG   2048   // 4*HU gate rows per (depth,stack)

typedef float f32x4 __attribute__((ext_vector_type(4)));
typedef short bf16x8 __attribute__((ext_vector_type(8)));

__device__ __forceinline__ short f2bf(float x) {
    union { float f; unsigned u; } v; v.f = x;
    unsigned r = v.u + 0x7fffu + ((v.u >> 16) & 1u);   // RNE
    return (short)(r >> 16);
}
__device__ __forceinline__ float sigm(float x)   { return 1.f / (1.f + __expf(-x)); }
__device__ __forceinline__ float tanh_f(float x) { return 2.f / (1.f + __expf(-2.f * x)) - 1.f; }

// async global->LDS, 16B per lane; LDS dest is wave-uniform base + lane*16.
__device__ __forceinline__ void async16(const void* g, void* l) {
    __builtin_amdgcn_global_load_lds((__attribute__((address_space(1))) void*)g,
                                     (__attribute__((address_space(3))) void*)l,
                                     16, 0, 0);
}

// counted-vmcnt barrier: wait own VMEM queue down to N, then rendezvous.
// After all waves pass, every issue older than the newest N (in each wave's
// identical issue stream) has landed in LDS.
#define PIPE_SYNC(N) asm volatile("s_waitcnt vmcnt(" #N ")\n\ts_barrier" ::: "memory")

// ---------------------------------------------------------------- flat f32 -> bf16
__global__ __launch_bounds__(256) void cvt_kernel(const float* __restrict__ src,
                                                  short* __restrict__ dst, long n) {
    long i = ((long)blockIdx.x * 256 + threadIdx.x) * 8;
    if (i >= n) return;
    float4 a = *(const float4*)(src + i);
    float4 b = *(const float4*)(src + i + 4);
    bf16x8 o;
    o[0] = f2bf(a.x); o[1] = f2bf(a.y); o[2] = f2bf(a.z); o[3] = f2bf(a.w);
    o[4] = f2bf(b.x); o[5] = f2bf(b.y); o[6] = f2bf(b.z); o[7] = f2bf(b.w);
    *(bf16x8*)(dst + i) = o;
}

// ---- strided: take first OHW cols of each SW-wide row (state[0,:,:,0:2048]) -> bf16
__global__ __launch_bounds__(256) void cvt_h_kernel(const float* __restrict__ src,
                                                    short* __restrict__ dst) {
    long i = ((long)blockIdx.x * 256 + threadIdx.x) * 8;   // over 2*B*OHW
    long row = i >> 11;              // /2048
    long c   = i & 2047;
    const float* s = src + row * SW + c;
    float4 a = *(const float4*)(s);
    float4 b = *(const float4*)(s + 4);
    bf16x8 o;
    o[0] = f2bf(a.x); o[1] = f2bf(a.y); o[2] = f2bf(a.z); o[3] = f2bf(a.w);
    o[4] = f2bf(b.x); o[5] = f2bf(b.y); o[6] = f2bf(b.z); o[7] = f2bf(b.w);
    *(bf16x8*)(dst + i) = o;
}

// 16-MFMA cluster (4 m-tiles x 2 n-tiles x 2 k-slices), setprio-wrapped (T5).
// AR0/N0 must be literals -> all acc indexing compile-time (no scratch).
#define MMA_BLK(BB, AR0, N0)                                                      \
  do {                                                                            \
    __builtin_amdgcn_s_setprio(1);                                                \
    _Pragma("unroll")                                                             \
    for (int mtl = 0; mtl < 4; ++mtl) {                                           \
      _Pragma("unroll")                                                           \
      for (int nn = 0; nn < 2; ++nn) {                                            \
        _Pragma("unroll")                                                         \
        for (int ks = 0; ks < 2; ++ks) {                                          \
          acc[(AR0) + mtl][(N0) + nn] = __builtin_amdgcn_mfma_f32_16x16x32_bf16(  \
              aR[mtl][ks], BB[nn][ks], acc[(AR0) + mtl][(N0) + nn], 0, 0, 0);     \
        }                                                                         \
      }                                                                           \
    }                                                                             \
    __builtin_amdgcn_s_setprio(0);                                                \
  } while (0)

// B-tile row rb (0..255) -> global gate row: gate=(rb>>4)&3, hid=h0+((rb>>6)<<4)+(rb&15)
#define GROW(rb) (((((rb) >> 4) & 3) << 9) + h0 + ((((rb) >> 6)) << 4) + ((rb) & 15))

// ---------------------------------------------------------------- fused gates GEMM + LSTM cell
// 256x256 tile, 8 waves (2Mx4N), BK=64, double-buffered 128 KiB LDS,
// counted-vmcnt pipelined schedule (T3+T4) + setprio (T5) + source-swizzled LDS (T2).
// Tile cols interleave gates: col n -> gate=(n>>4)&3, hid=h0+(n>>6)*16+(n&15),
// so each wave's 64-col span = all 4 gates x 16 hidden units (epilogue thread-local).
// K phases: tiles 0..15 = dec_input @ W_ih^T (K=1024), tiles 16..23 = hx @ W_hh^T (K=512).
__global__ __launch_bounds__(512, 2) void gates2_kernel(
    const short* __restrict__ A1, long a1_dstride,       // bf16 dec_input (row stride ISZ)
    const short* __restrict__ Hb,                        // bf16 h-state (2,B,OHW)
    const short* __restrict__ Wihb, const short* __restrict__ Whhb,
    const float* __restrict__ b_ih, const float* __restrict__ b_hh,
    const float* __restrict__ state,                     // f32 original (2,2,B,SW)
    float* __restrict__ out_ho, float* __restrict__ out_state,
    short* __restrict__ h0b,                             // bf16 h_out (stack0 only)
    int j)
{
    extern __shared__ short lds[];   // 2 bufs x (A 256x64 + B 256x64) bf16 = 131072 B

    const int tid  = threadIdx.x;
    const int wave = tid >> 6;
    const int lane = tid & 63;
    const int wm   = wave >> 2;      // 0..1  (m-half)
    const int wn   = wave & 3;       // 0..3  (n-quarter)
    const int ln16 = lane & 15;
    const int q    = (lane >> 4) & 3;

    // bijective XCD chunk swizzle (512 blocks, 512 % 8 == 0)
    const int id  = blockIdx.x;
    const int swz = (id & 7) * 64 + (id >> 3);
    const int M0  = (swz & 15) * 256;        // batch tile
    const int h0  = ((swz >> 4) & 7) * 64;   // hidden tile (64 units)
    const int d   = swz >> 7;                // depth
    const int s   = d * HU_;

    const short* A1d = A1 + (size_t)d * a1_dstride;
    const short* A2  = Hb + (size_t)j * B_ * OHW + s;                 // row stride OHW
    const short* W1  = Wihb + (size_t)(d * 2 + j) * NG * ISZ;
    const short* W2  = Whhb + (size_t)(d * 2 + j) * NG * HU_;
    const float* bi_ = b_ih + (size_t)(d * 2 + j) * NG;
    const float* bh_ = b_hh + (size_t)(d * 2 + j) * NG;

    // staging geometry: each issue = 512thr x 16B = 64 rows x 128B, linear LDS dest,
    // source col pre-swizzled (XOR 8-elem blocks) so swizzled layout lands via linear write.
    const int srow = tid >> 3;                                  // 0..63 row-in-issue
    const int scol = (((tid & 7) ^ ((tid >> 3) & 7)) << 3);     // swizzled source col (elems)

    // current-phase source pointers + per-thread row offsets (u32 element offsets)
    const short* As = A1d;
    const short* Bs = W1;
    unsigned aoff0 = (unsigned)((M0 +   0 + srow) * ISZ + scol);
    unsigned aoff1 = (unsigned)((M0 +  64 + srow) * ISZ + scol);
    unsigned aoff2 = (unsigned)((M0 + 128 + srow) * ISZ + scol);
    unsigned aoff3 = (unsigned)((M0 + 192 + srow) * ISZ + scol);
    unsigned boff0 = (unsigned)(GROW(      srow) * ISZ + scol);
    unsigned boff1 = (unsigned)(GROW( 64 + srow) * ISZ + scol);
    unsigned boff2 = (unsigned)(GROW(128 + srow) * ISZ + scol);
    unsigned boff3 = (unsigned)(GROW(192 + srow) * ISZ + scol);

    // ds_read swizzle slots: row&7 == ln16&7 for every fragment row
    const int swz0 = ((q    ) ^ (ln16 & 7)) << 4;
    const int swz1 = ((q + 4) ^ (ln16 & 7)) << 4;
    const char* ldsb = (const char*)lds;

    f32x4 acc[8][4];
#pragma unroll
    for (int i = 0; i < 8; ++i)
#pragma unroll
        for (int n = 0; n < 4; ++n) acc[i][n] = (f32x4){0.f, 0.f, 0.f, 0.f};

    bf16x8 aR[4][2];          // one m-half of A fragments (reused lo->hi)
    bf16x8 b01[2][2];         // n-tiles 0,1 (gates i,f)
    bf16x8 b23[2][2];         // n-tiles 2,3 (gates g,o)

    auto stA = [&](unsigned off, int it, int nbuf, int kofs) {
        async16(As + off + kofs, lds + nbuf * 32768 + (it * 64 + wave * 8) * 64);
    };
    auto stB = [&](unsigned off, int it, int nbuf, int kofs) {
        async16(Bs + off + kofs, lds + nbuf * 32768 + 16384 + (it * 64 + wave * 8) * 64);
    };
    auto rdA = [&](int buf, int hi) {
#pragma unroll
        for (int mtl = 0; mtl < 4; ++mtl) {
            const int row = wm * 128 + hi * 64 + mtl * 16 + ln16;
            aR[mtl][0] = *(const bf16x8*)(ldsb + buf * 65536 + row * 128 + swz0);
            aR[mtl][1] = *(const bf16x8*)(ldsb + buf * 65536 + row * 128 + swz1);
        }
    };
    auto rdB = [&](bf16x8 (&bb)[2][2], int buf, int nt0) {
#pragma unroll
        for (int nn = 0; nn < 2; ++nn) {
            const int row = wn * 64 + (nt0 + nn) * 16 + ln16;
            bb[nn][0] = *(const bf16x8*)(ldsb + buf * 65536 + 32768 + row * 128 + swz0);
            bb[nn][1] = *(const bf16x8*)(ldsb + buf * 65536 + 32768 + row * 128 + swz1);
        }
    };

    // prologue: stage tile 0 into buf 0 (issue order B0..B3,A0,A2,A1,A3), full drain
    stB(boff0, 0, 0, 0); stB(boff1, 1, 0, 0); stB(boff2, 2, 0, 0); stB(boff3, 3, 0, 0);
    stA(aoff0, 0, 0, 0); stA(aoff2, 2, 0, 0); stA(aoff1, 1, 0, 0); stA(aoff3, 3, 0, 0);
    PIPE_SYNC(0);

    // Per tile: 8 prefetch issues for t+1 at 2/phase; waits:
    //   mid-tile  vmcnt(4): outstanding = {A1,A3}(t) + {B0..B3}(t+1) = 6 -> A1,A3(t) land
    //   boundary  vmcnt(2): outstanding = 8 of (t+1) -> all but {A1,A3}(t+1) land
    auto do_tile = [&](int t, int kofs) {
        const int buf = t & 1, nbuf = buf ^ 1;
        // ph0: needs {B0..B3, A0, A2}(t) -- guaranteed by previous boundary sync
        stB(boff0, 0, nbuf, kofs); stB(boff1, 1, nbuf, kofs);
        rdA(buf, 0); rdB(b01, buf, 0);
        MMA_BLK(b01, 0, 0);
        // ph1: b23 rows covered by same B issues
        stB(boff2, 2, nbuf, kofs); stB(boff3, 3, nbuf, kofs);
        rdB(b23, buf, 2);
        MMA_BLK(b23, 0, 2);
        PIPE_SYNC(4);
        // ph2: a-hi = {A1,A3}(t), just guaranteed
        stA(aoff0, 0, nbuf, kofs); stA(aoff2, 2, nbuf, kofs);
        rdA(buf, 1);
        MMA_BLK(b23, 4, 2);
        // ph3: register-only
        stA(aoff1, 1, nbuf, kofs); stA(aoff3, 3, nbuf, kofs);
        MMA_BLK(b01, 4, 0);
        PIPE_SYNC(2);
    };

    // K phase 1: tiles 0..14 computed, staging tiles 1..15 (dec_input @ W_ih^T)
    for (int t = 0; t < 15; ++t) do_tile(t, (t + 1) * 64);

    // switch staging to K phase 2: hx @ W_hh^T
    As = A2; Bs = W2;
    aoff0 = (unsigned)((M0 +   0 + srow) * OHW + scol);
    aoff1 = (unsigned)((M0 +  64 + srow) * OHW + scol);
    aoff2 = (unsigned)((M0 + 128 + srow) * OHW + scol);
    aoff3 = (unsigned)((M0 + 192 + srow) * OHW + scol);
    boff0 = (unsigned)(GROW(      srow) * HU_ + scol);
    boff1 = (unsigned)(GROW( 64 + srow) * HU_ + scol);
    boff2 = (unsigned)(GROW(128 + srow) * HU_ + scol);
    boff3 = (unsigned)(GROW(192 + srow) * HU_ + scol);

    // tiles 15..22 computed, staging tiles 16..23 (kofs = (t+1-16)*64)
    for (int t = 15; t < 23; ++t) do_tile(t, (t - 15) * 64);

    // last tile (t = 23, buf 1), no prefetch -> drain before a-hi
    {
        rdA(1, 0); rdB(b01, 1, 0);
        MMA_BLK(b01, 0, 0);
        rdB(b23, 1, 2);
        MMA_BLK(b23, 0, 2);
        PIPE_SYNC(0);
        rdA(1, 1);
        MMA_BLK(b23, 4, 2);
        MMA_BLK(b01, 4, 0);
    }

    // epilogue: fused LSTM cell. D layout: col = lane&15, row = q*4 + reg.
    // acc[mt][nt]: nt == gate index (i,f,g,o); h fixed per thread.
    const int h   = h0 + wn * 16 + ln16;       // 0..511
    const int col = s + h;                     // 0..2047
    const float b_i = bi_[h]          + bh_[h];
    const float b_f = bi_[512 + h]    + bh_[512 + h];
    const float b_g = bi_[1024 + h]   + bh_[1024 + h];
    const float b_o = bi_[1536 + h]   + bh_[1536 + h];
#pragma unroll
    for (int mt = 0; mt < 8; ++mt) {
#pragma unroll
        for (int r = 0; r < 4; ++r) {
            const int m = M0 + wm * 128 + mt * 16 + q * 4 + r;
            const float hx = state[((size_t)(j)     * B_ + m) * SW + col];  // state[0,j]
            const float cx = state[((size_t)(2 + j) * B_ + m) * SW + col];  // state[1,j]
            const float gi = sigm(acc[mt][0][r] + b_i);
            const float gf = sigm(acc[mt][1][r] + b_f);
            const float gg = tanh_f(acc[mt][2][r] + b_g);
            const float go = sigm(acc[mt][3][r] + b_o);
            const float c_out = gf * cx + gi * gg;
            const float h_out = go * tanh_f(c_out);
            out_state[((size_t)(j)     * B_ + m) * OHW + col] = h_out + hx;  // newH[j]
            out_state[((size_t)(2 + j) * B_ + m) * OHW + col] = c_out;       // newC[j]
            if (j == 1) out_ho[(size_t)m * OHW + col] = h_out + hx;
            else        h0b[((size_t)d * B_ + m) * HU_ + h] = f2bf(h_out);   // pre-residual
        }
    }
}

// ---------------------------------------------------------------- proj: dec1 = input + h0 @ proj_W^T + proj_b (bf16 out)
__global__ __launch_bounds__(256) void proj_kernel(
    const short* __restrict__ h0b, const short* __restrict__ PWb,
    const float* __restrict__ input, const float* __restrict__ proj_b,
    short* __restrict__ dec1b)
{
    __shared__ __align__(16) short sA[128 * 64];
    __shared__ __align__(16) short sB[128 * 64];

    const int t    = threadIdx.x;
    const int wave = t >> 6, lane = t & 63;
    const int ln16 = lane & 15, q = lane >> 4;
    const int d  = blockIdx.z;
    const int M0 = blockIdx.x * 128;
    const int N0 = blockIdx.y * 128;

    const short* A = h0b + (size_t)d * B_ * HU_;

    const int srow = wave * 8 + (lane >> 3);
    const int scol = (((lane & 7) ^ (lane >> 3)) << 3);

    f32x4 acc[2][8];
#pragma unroll
    for (int mt = 0; mt < 2; mt++)
#pragma unroll
        for (int nt = 0; nt < 8; nt++) acc[mt][nt] = (f32x4){0.f, 0.f, 0.f, 0.f};

    for (int k0 = 0; k0 < HU_; k0 += 64) {
#pragma unroll
        for (int it = 0; it < 4; it++)
            async16(A + (size_t)(M0 + it * 32 + srow) * HU_ + k0 + scol,
                    &sA[(it * 32 + wave * 8) * 64]);
#pragma unroll
        for (int it = 0; it < 4; it++)
            async16(PWb + (size_t)(N0 + it * 32 + srow) * HU_ + k0 + scol,
                    &sB[(it * 32 + wave * 8) * 64]);
        __syncthreads();
#pragma unroll
        for (int ks = 0; ks < 2; ks++) {
            const int kb = ks * 4 + q;
            bf16x8 a[2], b[8];
#pragma unroll
            for (int mt = 0; mt < 2; mt++) {
                const int m = wave * 32 + mt * 16 + ln16;
                a[mt] = *(const bf16x8*)&sA[m * 64 + ((kb ^ (m & 7)) << 3)];
            }
#pragma unroll
            for (int nt = 0; nt < 8; nt++) {
                const int n = nt * 16 + ln16;
                b[nt] = *(const bf16x8*)&sB[n * 64 + ((kb ^ (n & 7)) << 3)];
            }
#pragma unroll
            for (int mt = 0; mt < 2; mt++)
#pragma unroll
                for (int nt = 0; nt < 8; nt++)
                    acc[mt][nt] = __builtin_amdgcn_mfma_f32_16x16x32_bf16(a[mt], b[nt], acc[mt][nt], 0, 0, 0);
        }
        __syncthreads();
    }

#pragma unroll
    for (int mt = 0; mt < 2; mt++) {
#pragma unroll
        for (int nt = 0; nt < 8; nt++) {
            const int n = N0 + nt * 16 + ln16;
            const float pb = proj_b[n];
#pragma unroll
            for (int r = 0; r < 4; r++) {
                const int m = M0 + wave * 32 + mt * 16 + q * 4 + r;
                const float y = acc[mt][nt][r] + input[(size_t)m * ISZ + n] + pb;
                dec1b[((size_t)d * B_ + m) * ISZ + n] = f2bf(y);
            }
        }
    }
}

// ---------------------------------------------------------------- launch
extern "C" void kernel_launch(void* const* d_in, const int* in_sizes, int n_in,
                              void* d_out, int out_size, void* d_ws, size_t ws_size,
                              hipStream_t stream)
{
    const float* input  = (const float*)d_in[0];
    const float* state  = (const float*)d_in[1];
    const float* W_ih   = (const float*)d_in[2];
    const float* W_hh   = (const float*)d_in[3];
    const float* b_ih   = (const float*)d_in[4];
    const float* b_hh   = (const float*)d_in[5];
    const float* proj_W = (const float*)d_in[6];
    const float* proj_b = (const float*)d_in[7];

    float* out_ho    = (float*)d_out;                    // (B, OHW)
    float* out_state = out_ho + (size_t)B_ * OHW;        // (2, 2, B, OHW)

    short* ws    = (short*)d_ws;
    short* Wihb  = ws;                                   // 8 x NG x ISZ   (32 MB)
    short* Whhb  = Wihb + (size_t)8 * NG * ISZ;          // 8 x NG x HU    (16 MB)
    short* PWb   = Whhb + (size_t)8 * NG * HU_;          // ISZ x HU       ( 1 MB)
    short* Hb    = PWb  + (size_t)ISZ * HU_;             // 2 x B x OHW    (32 MB)
    short* h0b   = Hb   + (size_t)2 * B_ * OHW;          // 4 x B x HU     (16 MB)
    short* dec1b = h0b  + (size_t)4 * B_ * HU_;          // 4 x B x ISZ    (32 MB)
    short* Xb    = dec1b;                                // B x ISZ — aliases dec1b head
                                                         // (Xb dead before proj writes dec1b)

    static bool s_attr = false;
    if (!s_attr) {
        (void)hipFuncSetAttribute(reinterpret_cast<const void*>(gates2_kernel),
                                  hipFuncAttributeMaxDynamicSharedMemorySize, 131072);
        s_attr = true;
    }

    {
        long n;
        n = (long)8 * NG * ISZ;  cvt_kernel<<<dim3((unsigned)(n / 8 / 256)), 256, 0, stream>>>(W_ih,   Wihb, n);
        n = (long)8 * NG * HU_;  cvt_kernel<<<dim3((unsigned)(n / 8 / 256)), 256, 0, stream>>>(W_hh,   Whhb, n);
        n = (long)ISZ * HU_;     cvt_kernel<<<dim3((unsigned)(n / 8 / 256)), 256, 0, stream>>>(proj_W, PWb,  n);
        n = (long)B_ * ISZ;      cvt_kernel<<<dim3((unsigned)(n / 8 / 256)), 256, 0, stream>>>(input,  Xb,   n);
        n = (long)2 * B_ * OHW;  cvt_h_kernel<<<dim3((unsigned)(n / 8 / 256)), 256, 0, stream>>>(state, Hb);
    }

    // stack 0 (all 4 depths): gates + cell, writes newH[0]/newC[0] and h0b
    gates2_kernel<<<dim3(512), dim3(512), 131072, stream>>>(Xb, 0L, Hb, Wihb, Whhb,
                                                            b_ih, b_hh, state,
                                                            out_ho, out_state, h0b, 0);
    // dec1 = input + h_out0 @ proj_W^T + proj_b (per depth), bf16
    proj_kernel<<<dim3(32, 8, 4), 256, 0, stream>>>(h0b, PWb, input, proj_b, dec1b);
    // stack 1 (all 4 depths): gates + cell, writes newH[1]/newC[1] and ho
    gates2_kernel<<<dim3(512), dim3(512), 131072, stream>>>(dec1b, (long)B_ * ISZ, Hb, Wihb, Whhb,
                                                            b_ih, b_hh, state,
                                                            out_ho, out_state, nullptr, 1);
}